// Round 1
// baseline (567.328 us; speedup 1.0000x reference)
//
#include <hip/hip_runtime.h>
#include <math.h>

#define GRIDN 16
#define PADN 32
#define NS 24
#define LDSW 33   // +1 pad: breaks 8-way bank conflicts on row-strided access

// ws layout: double sums[3] (Sp2, St2, Spt) | uint maxes[2] (Mp, Mt bits)

__global__ void init_ws(double* sums, unsigned int* maxes) {
    int t = threadIdx.x;
    if (t < 3) sums[t] = 0.0;
    if (t < 2) maxes[t] = 0u;
}

__global__ __launch_bounds__(256)
void loss_main(const float* __restrict__ output, const float* __restrict__ targets,
               double* __restrict__ sums, unsigned int* __restrict__ maxes) {
    __shared__ float sx[NS], sy[NS], sp[NS];
    __shared__ float tx[NS], ty[NS], ta[NS];
    __shared__ float gx[NS][PADN], gy[NS][PADN];
    __shared__ float dre[PADN * LDSW], dim[PADN * LDSW];
    __shared__ float gre[PADN * LDSW], gim[PADN * LDSW];
    __shared__ float pm[PADN * PADN];
    __shared__ float redm[4][5];

    const int b = blockIdx.x;
    const int t = threadIdx.x;
    const float* so = output + b * NS * 3;
    const float* tg = targets + b * NS * 3;

    // ---- load seeds (wave0) and targets (wave1) ----
    if (t < NS) {
        sx[t] = so[3 * t + 0];
        sy[t] = so[3 * t + 1];
        sp[t] = so[3 * t + 2];
    }
    if (t >= 64 && t < 64 + NS) {
        int s = t - 64;
        tx[s] = tg[3 * s + 0];
        ty[s] = tg[3 * s + 1];
        ta[s] = tg[3 * s + 2];
    }
    __syncthreads();

    // ---- Gaussian factor tables (amp folded into gx) ----
    for (int idx = t; idx < NS * PADN; idx += 256) {
        int s = idx >> 5, c = idx & 31;
        float dx = (float)c - tx[s];
        gx[s][c] = ta[s] * expf(dx * dx * (-1.0f / 4.5f));
        float dy = (float)c - ty[s];
        gy[s][c] = expf(dy * dy * (-1.0f / 4.5f));
    }

    // ---- phase map -> density (unit phasors) ----
    for (int q = 0; q < 4; ++q) {
        int idx = t + 256 * q;
        int y = idx >> 5, x = idx & 31;
        int dyc = y - 16, dxc = x - 16;
        int d2c = dyc * dyc + dxc * dxc;
        float ph = 0.0f;
        if (d2c <= 64) {                       // inside/on circle of radius 8
            if (y >= 8 && y < 24 && x >= 8 && x < 24) {
                // grid region: Voronoi argmin (first-min tie rule, sqrt to match ref)
                float fi = (float)(y - 8), fj = (float)(x - 8);
                int best = 0;
                float bd = 1e30f;
                for (int s = 0; s < NS; ++s) {
                    float ddx = fi - sx[s], ddy = fj - sy[s];
                    float d = sqrtf(ddx * ddx + ddy * ddy);
                    if (d < bd) { bd = d; best = s; }
                }
                ph = sp[best];
            } else {
                // padding pixels on the circle: label 0 -> phases[0]
                ph = sp[0];
            }
        }
        float sv, cv;
        sincosf(6.2831853071795864f * ph, &sv, &cv);
        dre[y * LDSW + x] = cv;
        dim[y * LDSW + x] = sv;
    }
    __syncthreads();

    // ---- DFT stage 1: rows.  G[y,l] = sum_x d[y,x] * e^{-2pi i l x / 32} ----
    {
        int y = t >> 3;
        int l0 = t & 7;
        float wr, wi;
        sincosf(-(float)l0 * (6.2831853071795864f / 32.0f), &wi, &wr); // e^{-i th}
        // w_j = w0 * (-i)^j  for l_j = l0 + 8j
        float wjr[4] = { wr,  wi, -wr, -wi };
        float wji[4] = { wi, -wr, -wi,  wr };
        float cr[4], ci[4], Gr[4], Gi[4];
#pragma unroll
        for (int j = 0; j < 4; ++j) { cr[j] = 1.0f; ci[j] = 0.0f; Gr[j] = 0.0f; Gi[j] = 0.0f; }
        const float* rrow = &dre[y * LDSW];
        const float* irow = &dim[y * LDSW];
        for (int x = 0; x < 32; ++x) {
            float a = rrow[x], bb = irow[x];
#pragma unroll
            for (int j = 0; j < 4; ++j) {
                Gr[j] += a * cr[j] - bb * ci[j];
                Gi[j] += a * ci[j] + bb * cr[j];
                float nr = cr[j] * wjr[j] - ci[j] * wji[j];
                float ni = cr[j] * wji[j] + ci[j] * wjr[j];
                cr[j] = nr; ci[j] = ni;
            }
        }
#pragma unroll
        for (int j = 0; j < 4; ++j) {
            int l = l0 + 8 * j;
            gre[y * LDSW + l] = Gr[j];
            gim[y * LDSW + l] = Gi[j];
        }
    }
    __syncthreads();

    // ---- DFT stage 2: cols.  H[k,l] = sum_y G[y,l] * e^{-2pi i k y / 32} ----
    // store |H| at fftshifted position
    {
        int l = t >> 3;
        int k0 = t & 7;
        float wr, wi;
        sincosf(-(float)k0 * (6.2831853071795864f / 32.0f), &wi, &wr);
        float wjr[4] = { wr,  wi, -wr, -wi };
        float wji[4] = { wi, -wr, -wi,  wr };
        float cr[4], ci[4], Hr[4], Hi[4];
#pragma unroll
        for (int j = 0; j < 4; ++j) { cr[j] = 1.0f; ci[j] = 0.0f; Hr[j] = 0.0f; Hi[j] = 0.0f; }
        for (int y = 0; y < 32; ++y) {
            float a = gre[y * LDSW + l], bb = gim[y * LDSW + l];
#pragma unroll
            for (int j = 0; j < 4; ++j) {
                Hr[j] += a * cr[j] - bb * ci[j];
                Hi[j] += a * ci[j] + bb * cr[j];
                float nr = cr[j] * wjr[j] - ci[j] * wji[j];
                float ni = cr[j] * wji[j] + ci[j] * wjr[j];
                cr[j] = nr; ci[j] = ni;
            }
        }
#pragma unroll
        for (int j = 0; j < 4; ++j) {
            int k = k0 + 8 * j;
            int u = (k + 16) & 31;
            int v = (l + 16) & 31;
            pm[u * 32 + v] = sqrtf(Hr[j] * Hr[j] + Hi[j] * Hi[j]);
        }
    }
    __syncthreads();

    // ---- target pattern + block-local reductions ----
    float mp = 0.f, mt = 0.f, sp2 = 0.f, st2 = 0.f, spt = 0.f;
    for (int q = 0; q < 4; ++q) {
        int idx = t + 256 * q;
        int r = idx >> 5, c = idx & 31;
        float td = 0.f;
#pragma unroll
        for (int s = 0; s < NS; ++s)
            td += gy[s][r] * gx[s][c];
        float p = pm[idx];
        mp = fmaxf(mp, p);
        mt = fmaxf(mt, td);
        sp2 += p * p;
        st2 += td * td;
        spt += p * td;
    }

    // wave (64-lane) reduce
    for (int off = 32; off > 0; off >>= 1) {
        mp  = fmaxf(mp, __shfl_down(mp, off));
        mt  = fmaxf(mt, __shfl_down(mt, off));
        sp2 += __shfl_down(sp2, off);
        st2 += __shfl_down(st2, off);
        spt += __shfl_down(spt, off);
    }
    int wave = t >> 6, lane = t & 63;
    if (lane == 0) {
        redm[wave][0] = mp; redm[wave][1] = mt;
        redm[wave][2] = sp2; redm[wave][3] = st2; redm[wave][4] = spt;
    }
    __syncthreads();
    if (t == 0) {
        for (int w = 1; w < 4; ++w) {
            mp = fmaxf(mp, redm[w][0]);
            mt = fmaxf(mt, redm[w][1]);
            sp2 += redm[w][2];
            st2 += redm[w][3];
            spt += redm[w][4];
        }
        atomicAdd(&sums[0], (double)sp2);
        atomicAdd(&sums[1], (double)st2);
        atomicAdd(&sums[2], (double)spt);
        atomicMax(&maxes[0], __float_as_uint(mp));  // all values >= 0
        atomicMax(&maxes[1], __float_as_uint(mt));
    }
}

__global__ void finalize_loss(const double* __restrict__ sums,
                              const unsigned int* __restrict__ maxes,
                              float* __restrict__ out) {
    if (threadIdx.x == 0 && blockIdx.x == 0) {
        double Sp2 = sums[0], St2 = sums[1], Spt = sums[2];
        double Mp = (double)__uint_as_float(maxes[0]);
        double Mt = (double)__uint_as_float(maxes[1]);
        // sum((P/Mp - T/Mt)^2) / sqrt(sum(P/Mp)^2 * sum(T/Mt)^2)
        //   = (Sp2*Mt/Mp + St2*Mp/Mt - 2*Spt) / sqrt(Sp2*St2)
        double loss = (Sp2 * (Mt / Mp) + St2 * (Mp / Mt) - 2.0 * Spt) / sqrt(Sp2 * St2);
        out[0] = (float)loss;
    }
}

extern "C" void kernel_launch(void* const* d_in, const int* in_sizes, int n_in,
                              void* d_out, int out_size, void* d_ws, size_t ws_size,
                              hipStream_t stream) {
    const float* output  = (const float*)d_in[0];
    const float* targets = (const float*)d_in[1];
    double* sums = (double*)d_ws;
    unsigned int* maxes = (unsigned int*)((char*)d_ws + 3 * sizeof(double));
    int B = in_sizes[0] / (NS * 3);

    init_ws<<<1, 64, 0, stream>>>(sums, maxes);
    loss_main<<<B, 256, 0, stream>>>(output, targets, sums, maxes);
    finalize_loss<<<1, 64, 0, stream>>>(sums, maxes, (float*)d_out);
}

// Round 2
// 552.729 us; speedup vs baseline: 1.0264x; 1.0264x over previous
//
#include <hip/hip_runtime.h>
#include <math.h>

#define NS 24

// ws layout: double sums[3] (Sp2, St2, Spt) | uint maxes[2] (Mp, Mt bits)

__global__ void init_ws(double* sums, unsigned int* maxes) {
    int t = threadIdx.x;
    if (t < 3) sums[t] = 0.0;
    if (t < 2) maxes[t] = 0u;
}

#define ROT() { float nr_ = cr*wr - ci*wi, ni_ = cr*wi + ci*wr; cr = nr_; ci = ni_; }

__global__ __launch_bounds__(256)
void loss_main(const float* __restrict__ output, const float* __restrict__ targets,
               double* __restrict__ sums, unsigned int* __restrict__ maxes) {
    __shared__ float sx[NS], sy[NS], sp[NS];
    __shared__ float tx[NS], ty[NS], ta[NS];
    __shared__ float gx[NS * 32], gy[NS * 32];   // separable gaussian factors (amp in gx)
    __shared__ float2 e2[16 * 33];               // e = phasor-1, rows y=8..23, stride 33
    __shared__ float gTre[32 * 20], gTim[32 * 20]; // stage-1 output, transposed [l][yy], stride 20
    __shared__ float pm[32 * 40];                // |pred| fftshifted, stride 40
    __shared__ float redm[4][5];

    const int b = blockIdx.x;
    const int t = threadIdx.x;
    const float* so = output + b * NS * 3;
    const float* tg = targets + b * NS * 3;

    if (t < NS) {
        sx[t] = so[3 * t + 0];
        sy[t] = so[3 * t + 1];
        sp[t] = so[3 * t + 2];
    }
    if (t >= 64 && t < 64 + NS) {
        int s = t - 64;
        tx[s] = tg[3 * s + 0];
        ty[s] = tg[3 * s + 1];
        ta[s] = tg[3 * s + 2];
    }
    __syncthreads();

    // ---- gaussian factor tables ----
    for (int idx = t; idx < NS * 32; idx += 256) {
        int s = idx >> 5, c = idx & 31;
        float dx = (float)c - tx[s];
        gx[idx] = ta[s] * __expf(dx * dx * (-1.0f / 4.5f));
        float dy = (float)c - ty[s];
        gy[idx] = __expf(dy * dy * (-1.0f / 4.5f));
    }

    // ---- e = density - 1 on rows y=8..23 (all other rows zero; y=24 analytic) ----
#pragma unroll
    for (int q = 0; q < 2; ++q) {
        int idx = t + 256 * q;           // 0..511
        int yy = idx >> 5, x = idx & 31;
        int y = yy + 8;
        int dyc = y - 16, dxc = x - 16;
        float2 e = make_float2(0.0f, 0.0f);
        if (dyc * dyc + dxc * dxc <= 64) {
            float ph;
            if (x < 24) {   // grid region (y in [8,24) guaranteed)
                float fi = (float)(y - 8), fj = (float)(x - 8);
                int best = 0;
                float bd = 1e30f;
                for (int s = 0; s < NS; ++s) {
                    float ddx = fi - sx[s], ddy = fj - sy[s];
                    float d = sqrtf(ddx * ddx + ddy * ddy); // sqrt: match ref tie ordering
                    if (d < bd) { bd = d; best = s; }
                }
                ph = sp[best];
            } else {
                ph = sp[0];  // padding circle pixel (16,24): label 0
            }
            float sv, cv;
            __sincosf(6.2831853071795864f * ph, &sv, &cv);
            e = make_float2(cv - 1.0f, sv);
        }
        e2[yy * 33 + x] = e;
    }
    __syncthreads();

    // ---- stage 1: row DFT over x=8..24. One chain -> outputs l0 and l0+16 ----
    {
        int yy = t >> 4;       // 0..15
        int l0 = t & 15;       // 0..15
        int m = l0 & 3;        // c(x=8) = (-i)^l0
        float cr = (m == 0) ? 1.f : (m == 2) ? -1.f : 0.f;
        float ci = (m == 1) ? -1.f : (m == 3) ? 1.f : 0.f;
        float wr, wi;
        __sincosf(-(float)l0 * 0.19634954084936207f, &wi, &wr); // e^{-2pi i l0/32}
        float g0r = 0, g0i = 0, g1r = 0, g1i = 0;
        const float2* row = &e2[yy * 33];
#pragma unroll
        for (int xp = 0; xp < 8; ++xp) {
            int x = 8 + 2 * xp;
            float2 a = row[x];
            float tr = a.x * cr - a.y * ci, ti = a.x * ci + a.y * cr;
            g0r += tr; g0i += ti; g1r += tr; g1i += ti;   // x even: (+1)^x
            ROT();
            float2 bb = row[x + 1];
            tr = bb.x * cr - bb.y * ci; ti = bb.x * ci + bb.y * cr;
            g0r += tr; g0i += ti; g1r -= tr; g1i -= ti;   // x odd: (-1)^x
            ROT();
        }
        {   // tail x = 24 (even)
            float2 a = row[24];
            float tr = a.x * cr - a.y * ci, ti = a.x * ci + a.y * cr;
            g0r += tr; g0i += ti; g1r += tr; g1i += ti;
        }
        gTre[l0 * 20 + yy] = g0r;        gTim[l0 * 20 + yy] = g0i;
        gTre[(l0 + 16) * 20 + yy] = g1r; gTim[(l0 + 16) * 20 + yy] = g1i;
    }
    __syncthreads();

    // ---- stage 2: col DFT over y=8..23 (+ analytic y=24 pixel + delta) ----
    {
        int l = t >> 3;      // 0..31
        int k0 = t & 7;      // 0..7 ; k = k0 + 8j
        int m = k0 & 3;      // c(y=8) = (-i)^k0
        float cr = (m == 0) ? 1.f : (m == 2) ? -1.f : 0.f;
        float ci = (m == 1) ? -1.f : (m == 3) ? 1.f : 0.f;
        float wr, wi;
        __sincosf(-(float)k0 * 0.19634954084936207f, &wi, &wr);
        float h0r = 0, h0i = 0, h1r = 0, h1i = 0, h2r = 0, h2i = 0, h3r = 0, h3i = 0;
#pragma unroll
        for (int c4 = 0; c4 < 4; ++c4) {
            float4 gr = *(const float4*)&gTre[l * 20 + 4 * c4];
            float4 gi = *(const float4*)&gTim[l * 20 + 4 * c4];
            float tr, ti;
            // p=0: factors all 1
            tr = gr.x * cr - gi.x * ci; ti = gr.x * ci + gi.x * cr;
            h0r += tr; h0i += ti;
            h1r += tr; h1i += ti;
            h2r += tr; h2i += ti;
            h3r += tr; h3i += ti;
            ROT();
            // p=1: j1:(-i)->(ti,-tr)  j2:(-1)  j3:(i)->(-ti,tr)
            tr = gr.y * cr - gi.y * ci; ti = gr.y * ci + gi.y * cr;
            h0r += tr; h0i += ti;
            h1r += ti; h1i -= tr;
            h2r -= tr; h2i -= ti;
            h3r -= ti; h3i += tr;
            ROT();
            // p=2: j1:(-1)  j2:(+1)  j3:(-1)
            tr = gr.z * cr - gi.z * ci; ti = gr.z * ci + gi.z * cr;
            h0r += tr; h0i += ti;
            h1r -= tr; h1i -= ti;
            h2r += tr; h2i += ti;
            h3r -= tr; h3i -= ti;
            ROT();
            // p=3: j1:(i)->(-ti,tr)  j2:(-1)  j3:(-i)->(ti,-tr)
            tr = gr.w * cr - gi.w * ci; ti = gr.w * ci + gi.w * cr;
            h0r += tr; h0i += ti;
            h1r -= ti; h1i += tr;
            h2r -= tr; h2i -= ti;
            h3r += ti; h3i -= tr;
            ROT();
        }
        // analytic pixel (24,16): e24 * (-1)^l * i^k0  (same for all j since i^(8j)=1)
        {
            float sv0, cv0;
            __sincosf(6.2831853071795864f * sp[0], &sv0, &cv0);
            float e24r = cv0 - 1.0f, e24i = sv0;
            float ar2 = (m == 0) ? 1.f : (m == 2) ? -1.f : 0.f;  // i^k0
            float ai2 = (m == 1) ? 1.f : (m == 3) ? -1.f : 0.f;
            float sgn = (l & 1) ? -1.f : 1.f;
            float Tr = sgn * (e24r * ar2 - e24i * ai2);
            float Ti = sgn * (e24r * ai2 + e24i * ar2);
            h0r += Tr; h0i += Ti;
            h1r += Tr; h1i += Ti;
            h2r += Tr; h2i += Ti;
            h3r += Tr; h3i += Ti;
        }
        if (t == 0) h0r += 1024.0f;   // FFT(ones) delta at (k,l)=(0,0)
        int v = (l + 16) & 31;
        pm[((k0 + 16) & 31) * 40 + v] = sqrtf(h0r * h0r + h0i * h0i);
        pm[((k0 + 24) & 31) * 40 + v] = sqrtf(h1r * h1r + h1i * h1i);
        pm[(k0)        * 40 + v]      = sqrtf(h2r * h2r + h2i * h2i);
        pm[((k0 + 8))  * 40 + v]      = sqrtf(h3r * h3r + h3i * h3i);
    }
    __syncthreads();

    // ---- target + block reductions: 4 consecutive pixels per thread ----
    float mp = 0.f, mt = 0.f, sp2 = 0.f, st2 = 0.f, spt = 0.f;
    {
        int r = t >> 3;
        int c0 = (t & 7) * 4;
        float4 p4 = *(const float4*)&pm[r * 40 + c0];
        float t0 = 0, t1 = 0, t2 = 0, t3 = 0;
#pragma unroll
        for (int s = 0; s < NS; ++s) {
            float gyv = gy[s * 32 + r];
            float4 g4 = *(const float4*)&gx[s * 32 + c0];
            t0 += gyv * g4.x; t1 += gyv * g4.y;
            t2 += gyv * g4.z; t3 += gyv * g4.w;
        }
        mp = fmaxf(fmaxf(p4.x, p4.y), fmaxf(p4.z, p4.w));
        mt = fmaxf(fmaxf(t0, t1), fmaxf(t2, t3));
        sp2 = p4.x * p4.x + p4.y * p4.y + p4.z * p4.z + p4.w * p4.w;
        st2 = t0 * t0 + t1 * t1 + t2 * t2 + t3 * t3;
        spt = p4.x * t0 + p4.y * t1 + p4.z * t2 + p4.w * t3;
    }

    for (int off = 32; off > 0; off >>= 1) {
        mp  = fmaxf(mp, __shfl_down(mp, off));
        mt  = fmaxf(mt, __shfl_down(mt, off));
        sp2 += __shfl_down(sp2, off);
        st2 += __shfl_down(st2, off);
        spt += __shfl_down(spt, off);
    }
    int wave = t >> 6, lane = t & 63;
    if (lane == 0) {
        redm[wave][0] = mp; redm[wave][1] = mt;
        redm[wave][2] = sp2; redm[wave][3] = st2; redm[wave][4] = spt;
    }
    __syncthreads();
    if (t == 0) {
        for (int w = 1; w < 4; ++w) {
            mp = fmaxf(mp, redm[w][0]);
            mt = fmaxf(mt, redm[w][1]);
            sp2 += redm[w][2];
            st2 += redm[w][3];
            spt += redm[w][4];
        }
        atomicAdd(&sums[0], (double)sp2);
        atomicAdd(&sums[1], (double)st2);
        atomicAdd(&sums[2], (double)spt);
        atomicMax(&maxes[0], __float_as_uint(mp));
        atomicMax(&maxes[1], __float_as_uint(mt));
    }
}

__global__ void finalize_loss(const double* __restrict__ sums,
                              const unsigned int* __restrict__ maxes,
                              float* __restrict__ out) {
    if (threadIdx.x == 0 && blockIdx.x == 0) {
        double Sp2 = sums[0], St2 = sums[1], Spt = sums[2];
        double Mp = (double)__uint_as_float(maxes[0]);
        double Mt = (double)__uint_as_float(maxes[1]);
        double loss = (Sp2 * (Mt / Mp) + St2 * (Mp / Mt) - 2.0 * Spt) / sqrt(Sp2 * St2);
        out[0] = (float)loss;
    }
}

extern "C" void kernel_launch(void* const* d_in, const int* in_sizes, int n_in,
                              void* d_out, int out_size, void* d_ws, size_t ws_size,
                              hipStream_t stream) {
    const float* output  = (const float*)d_in[0];
    const float* targets = (const float*)d_in[1];
    double* sums = (double*)d_ws;
    unsigned int* maxes = (unsigned int*)((char*)d_ws + 3 * sizeof(double));
    int B = in_sizes[0] / (NS * 3);

    init_ws<<<1, 64, 0, stream>>>(sums, maxes);
    loss_main<<<B, 256, 0, stream>>>(output, targets, sums, maxes);
    finalize_loss<<<1, 64, 0, stream>>>(sums, maxes, (float*)d_out);
}

// Round 3
// 151.912 us; speedup vs baseline: 3.7346x; 3.6385x over previous
//
#include <hip/hip_runtime.h>
#include <math.h>

#define NS 24

// ws layout (SoA): float partials[5][B] : rows = {sp2, st2, spt, mp, mt}

#define ROT() { float nr_ = cr*wr - ci*wi, ni_ = cr*wi + ci*wr; cr = nr_; ci = ni_; }

__global__ __launch_bounds__(256)
void loss_main(const float* __restrict__ output, const float* __restrict__ targets,
               float* __restrict__ partials, int B) {
    __shared__ float sx[NS], sy[NS], sp[NS];
    __shared__ float tx[NS], ty[NS], ta[NS];
    __shared__ float gx[NS * 32], gy[NS * 32];   // separable gaussian factors (amp in gx)
    __shared__ float2 e2[16 * 33];               // e = phasor-1, rows y=8..23, stride 33
    __shared__ float gTre[32 * 20], gTim[32 * 20]; // stage-1 out, transposed [l][yy], stride 20
    __shared__ float pm[32 * 40];                // |pred| fftshifted, stride 40
    __shared__ float redm[4][5];

    const int b = blockIdx.x;
    const int t = threadIdx.x;
    const float* so = output + b * NS * 3;
    const float* tg = targets + b * NS * 3;

    if (t < NS) {
        sx[t] = so[3 * t + 0];
        sy[t] = so[3 * t + 1];
        sp[t] = so[3 * t + 2];
    }
    if (t >= 64 && t < 64 + NS) {
        int s = t - 64;
        tx[s] = tg[3 * s + 0];
        ty[s] = tg[3 * s + 1];
        ta[s] = tg[3 * s + 2];
    }
    __syncthreads();

    // ---- gaussian factor tables ----
    for (int idx = t; idx < NS * 32; idx += 256) {
        int s = idx >> 5, c = idx & 31;
        float dx = (float)c - tx[s];
        gx[idx] = ta[s] * __expf(dx * dx * (-1.0f / 4.5f));
        float dy = (float)c - ty[s];
        gy[idx] = __expf(dy * dy * (-1.0f / 4.5f));
    }

    // ---- e = density - 1 on rows y=8..23 (other rows zero; y=24 analytic) ----
#pragma unroll
    for (int q = 0; q < 2; ++q) {
        int idx = t + 256 * q;           // 0..511
        int yy = idx >> 5, x = idx & 31;
        int y = yy + 8;
        int dyc = y - 16, dxc = x - 16;
        float2 e = make_float2(0.0f, 0.0f);
        if (dyc * dyc + dxc * dxc <= 64) {
            float ph;
            if (x < 24) {   // grid region (y in [8,24) guaranteed)
                float fi = (float)(y - 8), fj = (float)(x - 8);
                int best = 0;
                float bd = 1e30f;
                for (int s = 0; s < NS; ++s) {
                    float ddx = fi - sx[s], ddy = fj - sy[s];
                    float d = sqrtf(ddx * ddx + ddy * ddy); // sqrt: match ref tie ordering
                    if (d < bd) { bd = d; best = s; }
                }
                ph = sp[best];
            } else {
                ph = sp[0];  // padding circle pixel (16,24): label 0
            }
            float sv, cv;
            __sincosf(6.2831853071795864f * ph, &sv, &cv);
            e = make_float2(cv - 1.0f, sv);
        }
        e2[yy * 33 + x] = e;
    }
    __syncthreads();

    // ---- stage 1: row DFT over x=8..24. One chain -> outputs l0 and l0+16 ----
    {
        int yy = t >> 4;       // 0..15
        int l0 = t & 15;       // 0..15
        int m = l0 & 3;        // c(x=8) = (-i)^l0
        float cr = (m == 0) ? 1.f : (m == 2) ? -1.f : 0.f;
        float ci = (m == 1) ? -1.f : (m == 3) ? 1.f : 0.f;
        float wr, wi;
        __sincosf(-(float)l0 * 0.19634954084936207f, &wi, &wr); // e^{-2pi i l0/32}
        float g0r = 0, g0i = 0, g1r = 0, g1i = 0;
        const float2* row = &e2[yy * 33];
#pragma unroll
        for (int xp = 0; xp < 8; ++xp) {
            int x = 8 + 2 * xp;
            float2 a = row[x];
            float tr = a.x * cr - a.y * ci, ti = a.x * ci + a.y * cr;
            g0r += tr; g0i += ti; g1r += tr; g1i += ti;   // x even: (+1)^x
            ROT();
            float2 bb = row[x + 1];
            tr = bb.x * cr - bb.y * ci; ti = bb.x * ci + bb.y * cr;
            g0r += tr; g0i += ti; g1r -= tr; g1i -= ti;   // x odd: (-1)^x
            ROT();
        }
        {   // tail x = 24 (even)
            float2 a = row[24];
            float tr = a.x * cr - a.y * ci, ti = a.x * ci + a.y * cr;
            g0r += tr; g0i += ti; g1r += tr; g1i += ti;
        }
        gTre[l0 * 20 + yy] = g0r;        gTim[l0 * 20 + yy] = g0i;
        gTre[(l0 + 16) * 20 + yy] = g1r; gTim[(l0 + 16) * 20 + yy] = g1i;
    }
    __syncthreads();

    // ---- stage 2: col DFT over y=8..23 (+ analytic y=24 pixel + delta) ----
    {
        int l = t >> 3;      // 0..31
        int k0 = t & 7;      // 0..7 ; k = k0 + 8j
        int m = k0 & 3;      // c(y=8) = (-i)^k0
        float cr = (m == 0) ? 1.f : (m == 2) ? -1.f : 0.f;
        float ci = (m == 1) ? -1.f : (m == 3) ? 1.f : 0.f;
        float wr, wi;
        __sincosf(-(float)k0 * 0.19634954084936207f, &wi, &wr);
        float h0r = 0, h0i = 0, h1r = 0, h1i = 0, h2r = 0, h2i = 0, h3r = 0, h3i = 0;
#pragma unroll
        for (int c4 = 0; c4 < 4; ++c4) {
            float4 gr = *(const float4*)&gTre[l * 20 + 4 * c4];
            float4 gi = *(const float4*)&gTim[l * 20 + 4 * c4];
            float tr, ti;
            // p=0: factors all 1
            tr = gr.x * cr - gi.x * ci; ti = gr.x * ci + gi.x * cr;
            h0r += tr; h0i += ti;
            h1r += tr; h1i += ti;
            h2r += tr; h2i += ti;
            h3r += tr; h3i += ti;
            ROT();
            // p=1: j1:(-i)->(ti,-tr)  j2:(-1)  j3:(i)->(-ti,tr)
            tr = gr.y * cr - gi.y * ci; ti = gr.y * ci + gi.y * cr;
            h0r += tr; h0i += ti;
            h1r += ti; h1i -= tr;
            h2r -= tr; h2i -= ti;
            h3r -= ti; h3i += tr;
            ROT();
            // p=2: j1:(-1)  j2:(+1)  j3:(-1)
            tr = gr.z * cr - gi.z * ci; ti = gr.z * ci + gi.z * cr;
            h0r += tr; h0i += ti;
            h1r -= tr; h1i -= ti;
            h2r += tr; h2i += ti;
            h3r -= tr; h3i -= ti;
            ROT();
            // p=3: j1:(i)->(-ti,tr)  j2:(-1)  j3:(-i)->(ti,-tr)
            tr = gr.w * cr - gi.w * ci; ti = gr.w * ci + gi.w * cr;
            h0r += tr; h0i += ti;
            h1r -= ti; h1i += tr;
            h2r -= tr; h2i -= ti;
            h3r += ti; h3i -= tr;
            ROT();
        }
        // analytic pixel (24,16): e24 * (-1)^l * i^k0  (same for all j: i^(8j)=1)
        {
            float sv0, cv0;
            __sincosf(6.2831853071795864f * sp[0], &sv0, &cv0);
            float e24r = cv0 - 1.0f, e24i = sv0;
            float ar2 = (m == 0) ? 1.f : (m == 2) ? -1.f : 0.f;  // i^k0
            float ai2 = (m == 1) ? 1.f : (m == 3) ? -1.f : 0.f;
            float sgn = (l & 1) ? -1.f : 1.f;
            float Tr = sgn * (e24r * ar2 - e24i * ai2);
            float Ti = sgn * (e24r * ai2 + e24i * ar2);
            h0r += Tr; h0i += Ti;
            h1r += Tr; h1i += Ti;
            h2r += Tr; h2i += Ti;
            h3r += Tr; h3i += Ti;
        }
        if (t == 0) h0r += 1024.0f;   // FFT(ones) delta at (k,l)=(0,0)
        int v = (l + 16) & 31;
        pm[((k0 + 16) & 31) * 40 + v] = sqrtf(h0r * h0r + h0i * h0i);
        pm[((k0 + 24) & 31) * 40 + v] = sqrtf(h1r * h1r + h1i * h1i);
        pm[(k0)        * 40 + v]      = sqrtf(h2r * h2r + h2i * h2i);
        pm[((k0 + 8))  * 40 + v]      = sqrtf(h3r * h3r + h3i * h3i);
    }
    __syncthreads();

    // ---- target + block reductions: 4 consecutive pixels per thread ----
    float mp = 0.f, mt = 0.f, sp2 = 0.f, st2 = 0.f, spt = 0.f;
    {
        int r = t >> 3;
        int c0 = (t & 7) * 4;
        float4 p4 = *(const float4*)&pm[r * 40 + c0];
        float t0 = 0, t1 = 0, t2 = 0, t3 = 0;
#pragma unroll
        for (int s = 0; s < NS; ++s) {
            float gyv = gy[s * 32 + r];
            float4 g4 = *(const float4*)&gx[s * 32 + c0];
            t0 += gyv * g4.x; t1 += gyv * g4.y;
            t2 += gyv * g4.z; t3 += gyv * g4.w;
        }
        mp = fmaxf(fmaxf(p4.x, p4.y), fmaxf(p4.z, p4.w));
        mt = fmaxf(fmaxf(t0, t1), fmaxf(t2, t3));
        sp2 = p4.x * p4.x + p4.y * p4.y + p4.z * p4.z + p4.w * p4.w;
        st2 = t0 * t0 + t1 * t1 + t2 * t2 + t3 * t3;
        spt = p4.x * t0 + p4.y * t1 + p4.z * t2 + p4.w * t3;
    }

    for (int off = 32; off > 0; off >>= 1) {
        mp  = fmaxf(mp, __shfl_down(mp, off));
        mt  = fmaxf(mt, __shfl_down(mt, off));
        sp2 += __shfl_down(sp2, off);
        st2 += __shfl_down(st2, off);
        spt += __shfl_down(spt, off);
    }
    int wave = t >> 6, lane = t & 63;
    if (lane == 0) {
        redm[wave][0] = sp2; redm[wave][1] = st2; redm[wave][2] = spt;
        redm[wave][3] = mp;  redm[wave][4] = mt;
    }
    __syncthreads();
    if (t == 0) {
        for (int w = 1; w < 4; ++w) {
            sp2 += redm[w][0];
            st2 += redm[w][1];
            spt += redm[w][2];
            mp = fmaxf(mp, redm[w][3]);
            mt = fmaxf(mt, redm[w][4]);
        }
        // plain stores to private slots -- NO atomics (round-2's 500us floor
        // was ~41k same-cacheline device atomics serializing at ~12ns each)
        partials[0 * B + b] = sp2;
        partials[1 * B + b] = st2;
        partials[2 * B + b] = spt;
        partials[3 * B + b] = mp;
        partials[4 * B + b] = mt;
    }
}

__global__ __launch_bounds__(1024)
void finalize_loss(const float* __restrict__ partials, float* __restrict__ out, int B) {
    __shared__ double reds[16][3];
    __shared__ float redx[16][2];
    const int t = threadIdx.x;
    double sp2 = 0.0, st2 = 0.0, spt = 0.0;
    float mp = 0.f, mt = 0.f;
    for (int i = t; i < B; i += 1024) {
        sp2 += (double)partials[0 * B + i];
        st2 += (double)partials[1 * B + i];
        spt += (double)partials[2 * B + i];
        mp = fmaxf(mp, partials[3 * B + i]);
        mt = fmaxf(mt, partials[4 * B + i]);
    }
    for (int off = 32; off > 0; off >>= 1) {
        sp2 += __shfl_down(sp2, off);
        st2 += __shfl_down(st2, off);
        spt += __shfl_down(spt, off);
        mp = fmaxf(mp, __shfl_down(mp, off));
        mt = fmaxf(mt, __shfl_down(mt, off));
    }
    int wave = t >> 6, lane = t & 63;
    if (lane == 0) {
        reds[wave][0] = sp2; reds[wave][1] = st2; reds[wave][2] = spt;
        redx[wave][0] = mp;  redx[wave][1] = mt;
    }
    __syncthreads();
    if (t == 0) {
        for (int w = 1; w < 16; ++w) {
            sp2 += reds[w][0];
            st2 += reds[w][1];
            spt += reds[w][2];
            mp = fmaxf(mp, redx[w][0]);
            mt = fmaxf(mt, redx[w][1]);
        }
        double Mp = (double)mp, Mt = (double)mt;
        double loss = (sp2 * (Mt / Mp) + st2 * (Mp / Mt) - 2.0 * spt) / sqrt(sp2 * st2);
        out[0] = (float)loss;
    }
}

extern "C" void kernel_launch(void* const* d_in, const int* in_sizes, int n_in,
                              void* d_out, int out_size, void* d_ws, size_t ws_size,
                              hipStream_t stream) {
    const float* output  = (const float*)d_in[0];
    const float* targets = (const float*)d_in[1];
    float* partials = (float*)d_ws;     // 5 * B floats
    int B = in_sizes[0] / (NS * 3);

    loss_main<<<B, 256, 0, stream>>>(output, targets, partials, B);
    finalize_loss<<<1, 1024, 0, stream>>>(partials, (float*)d_out, B);
}